// Round 7
// baseline (249.410 us; speedup 1.0000x reference)
//
#include <hip/hip_runtime.h>
#include <stdint.h>

// MHA forward, B=8 T=1024 C=1024 H=16 D=64.
// cast3 (w_qkv emitted k-block-transposed B'[k/32][n][32]) ->
// QKV GEMM (256x128 tile, 8 waves, A via 3-slot LDS rotation, B DIRECT from
// global (coalesced 1KB/wave loads, reg ping-pong, L1 dedups x4 wave reuse) —
// LDS pipe now A-only 48KB, MFMA-bound target)
// -> flash attention (3-slot K/V rotation + tile-pair pipelining)
// -> proj GEMM (BM=128, 4 waves, 512 blocks = 2/CU, fp32 +bias). 4 launches.

#define Bn 8
#define Tn 1024
#define Cn 1024
#define Hn 16
#define Dn 64
#define Mn (Bn * Tn)      // 8192
#define NQKV (3 * Cn)     // 3072
#define QKS 2048          // packed QK row stride

typedef unsigned short u16;
typedef float f32x4 __attribute__((ext_vector_type(4)));
typedef __bf16 bf16x8 __attribute__((ext_vector_type(8)));
typedef unsigned short ushx8 __attribute__((ext_vector_type(8)));
typedef unsigned short ushx4 __attribute__((ext_vector_type(4)));

__device__ __forceinline__ u16 f2bf(float f) {
  unsigned int u = __float_as_uint(f);
  u += 0x7fffu + ((u >> 16) & 1u);   // RTN-even
  return (u16)(u >> 16);
}
__device__ __forceinline__ u16 f2bf_rna(float f) {
  return (u16)((__float_as_uint(f) + 0x8000u) >> 16);
}

__device__ __forceinline__ f32x4 mfma_bf16(ushx8 a, ushx8 b, f32x4 c) {
  return __builtin_amdgcn_mfma_f32_16x16x32_bf16(
      __builtin_bit_cast(bf16x8, a), __builtin_bit_cast(bf16x8, b), c, 0, 0, 0);
}

// async global->LDS, 16B per lane; LDS dest = wave-uniform base + lane*16 (m104)
__device__ __forceinline__ void async16(const u16* g, u16* l) {
  __builtin_amdgcn_global_load_lds(
      (__attribute__((address_space(1))) void*)(void*)g,
      (__attribute__((address_space(3))) void*)l, 16, 0, 0);
}

// ---- DPP 16-lane butterfly reductions (VALU-rate, no LDS pipe) ----
template <int CTRL>
__device__ __forceinline__ float dppmov(float v) {
  return __builtin_bit_cast(float, __builtin_amdgcn_update_dpp(
      0, __builtin_bit_cast(int, v), CTRL, 0xf, 0xf, true));
}
__device__ __forceinline__ float red16max(float v) {
  v = fmaxf(v, dppmov<0xB1>(v));
  v = fmaxf(v, dppmov<0x4E>(v));
  v = fmaxf(v, dppmov<0x141>(v));
  v = fmaxf(v, dppmov<0x140>(v));
  return v;
}
__device__ __forceinline__ float red16sum(float v) {
  v += dppmov<0xB1>(v);
  v += dppmov<0x4E>(v);
  v += dppmov<0x141>(v);
  v += dppmov<0x140>(v);
  return v;
}

// ---------------- fused cast fp32 -> bf16 (3 tensors, 1 launch) ----------------
// Tensor b (w_qkv) is emitted K-BLOCK-TRANSPOSED: B'[kb][n][32] with kb=k/32,
// so the GEMM's B-fragment reads are contiguous 1KB per wave-instruction.
__global__ void cast3_kernel(const float* __restrict__ a, u16* __restrict__ oa, int na4,
                             const float* __restrict__ b, u16* __restrict__ ob, int nb4,
                             const float* __restrict__ c, u16* __restrict__ oc, int nc4) {
  int i = blockIdx.x * blockDim.x + threadIdx.x;
  if (i < na4) {
    float4 v = ((const float4*)a)[i];
    ushx4 o = { f2bf(v.x), f2bf(v.y), f2bf(v.z), f2bf(v.w) };
    ((ushx4*)oa)[i] = o;
  } else if (i < na4 + nb4) {
    i -= na4;
    float4 v = ((const float4*)b)[i];
    ushx4 o = { f2bf(v.x), f2bf(v.y), f2bf(v.z), f2bf(v.w) };
    const int n = i >> 8;          // row of w_qkv (output col), K=1024 -> 256 f4
    const int k4 = i & 255;
    const int kb = k4 >> 3;        // k/32
    const int kin = (k4 & 7) * 4;  // k%32
    *(ushx4*)&ob[((size_t)kb * NQKV + n) * 32 + kin] = o;
  } else if (i < na4 + nb4 + nc4) {
    i -= na4 + nb4;
    float4 v = ((const float4*)c)[i];
    ushx4 o = { f2bf(v.x), f2bf(v.y), f2bf(v.z), f2bf(v.w) };
    ((ushx4*)oc)[i] = o;
  }
}

#define SLOG2E 0.18033688011112042f

// ---------------- QKV GEMM: 256x128, 8 waves, A:LDS 3-slot, B:global-direct -------
// 512 threads = 8 waves (4 M x 2 N); per-wave 64x64 = acc[4][4].
// LDS 48 KiB: A only, 3 slots x [256][32] u16, chunk swizzle q^((row>>1)&3).
// B'[kb][n][32]: per phase each wave loads 4 x ushx8 (16 cols x 64B = 1KB
// contiguous). wr-quads (4 waves) read identical B bytes -> L1 dedup.
// Reg ping-pong: phase p consumes BC (loaded at p-1), issues BN for p+1.
// Compiler auto-waitcnt covers the reg loads; manual end-phase vmcnt(6)
// (= this phase's 4 B + 2 A-DMA) confirms As(p-1) [h=p+1] before the closing
// barrier. Prologue [As(h0)2, B(0)4, As(h1)2] + vmcnt(6) confirms h0.
// Slot rotation: phase p reads slot p%3 (h=p), stages h=min(p+2,31)->(p+2)%3.
__global__ __launch_bounds__(512, 4) void gemm_qkv_k(
    const u16* __restrict__ A, const u16* __restrict__ Bw,
    u16* __restrict__ qk, u16* __restrict__ vt) {
  __shared__ alignas(16) u16 lds[24576];  // 48 KiB (A only)

  const int tid = threadIdx.x;
  const int lane = tid & 63;
  const int wv = tid >> 6;       // 0..7
  const int quad = lane >> 4;
  const int l16 = lane & 15;
  const int wr = wv >> 1;        // 0..3 (M)
  const int wc = wv & 1;         // 0..1 (N)

  // XCD chunk map: xcd = bid&7 owns 4 consecutive 256-row m-tiles x all
  // n-tiles, m-fastest (A chunk 2 MiB fits XCD L2; B panel reused 4x).
  const int xcd = blockIdx.x & 7;
  const int loc = blockIdx.x >> 3;
  const int m0 = (xcd * 4 + (loc & 3)) * 256;
  const int n0 = (loc >> 2) * 128;

  const u16* gA = A + (size_t)m0 * Cn;

  const int r0s = tid >> 2;
  const int q0s = (tid & 3) ^ ((r0s >> 1) & 3);
  const int c1s = 512 + tid;
  const int r1s = c1s >> 2;
  const int q1s = (c1s & 3) ^ ((r1s >> 1) & 3);
  const int so0 = r0s * Cn + q0s * 8;
  const int so1 = r1s * Cn + q1s * 8;

  auto stageA = [&](int slot, int h) {
    u16* dst = lds + slot * 8192 + tid * 8;
    const u16* src = gA + (h >> 1) * 64 + (h & 1) * 32;
    async16(src + so0, dst);
    async16(src + so1, dst + 4096);
  };

  // B base: col0 = n0 + wc*64 + l16; frag(ni,p) at B'[(p*3072+col0+ni*16)*32+quad*8]
  const size_t bq0 = (size_t)(n0 + wc * 64 + l16) * 32 + quad * 8;
  const u16* bbase = Bw + bq0;

  const int sread = (quad ^ ((l16 >> 1) & 3)) * 8;
  const int aoff = (wr * 64 + l16) * 32 + sread;

  f32x4 acc[4][4];
#pragma unroll
  for (int i = 0; i < 4; ++i)
#pragma unroll
    for (int jj = 0; jj < 4; ++jj) acc[i][jj] = (f32x4){0.f, 0.f, 0.f, 0.f};
  ushx8 af[4], bcur[4], bnxt[4];

  // prologue: As(h0), B(0)->bcur, As(h1); vmcnt(6) confirms h0
  stageA(0, 0);
#pragma unroll
  for (int ni = 0; ni < 4; ++ni)
    bcur[ni] = *(const ushx8*)(bbase + ni * 512);
  stageA(1, 1);
  asm volatile("s_waitcnt vmcnt(6)" ::: "memory");
  __builtin_amdgcn_s_barrier();
  asm volatile("" ::: "memory");

#define PH(slot, sslot, p, BC, BN)                                             \
  {                                                                            \
    const u16* ab_ = lds + (slot) * 8192 + aoff;                               \
    af[0] = *(const ushx8*)(ab_);                                              \
    af[1] = *(const ushx8*)(ab_ + 512);                                        \
    af[2] = *(const ushx8*)(ab_ + 1024);                                       \
    af[3] = *(const ushx8*)(ab_ + 1536);                                       \
    {                                                                          \
      const int kb_ = ((p) + 1 < 32) ? (p) + 1 : 31;                           \
      const u16* bp_ = bbase + (size_t)kb_ * (NQKV * 32);                      \
      BN[0] = *(const ushx8*)(bp_);                                            \
      BN[1] = *(const ushx8*)(bp_ + 512);                                      \
      BN[2] = *(const ushx8*)(bp_ + 1024);                                     \
      BN[3] = *(const ushx8*)(bp_ + 1536);                                     \
    }                                                                          \
    {                                                                          \
      const int hd_ = ((p) + 2 < 32) ? (p) + 2 : 31;                           \
      stageA((sslot), hd_);                                                    \
    }                                                                          \
    asm volatile("" ::: "memory");                                             \
    __builtin_amdgcn_s_barrier();                                              \
    asm volatile("s_waitcnt lgkmcnt(0)" ::: "memory");                         \
    __builtin_amdgcn_s_setprio(1);                                             \
    _Pragma("unroll") for (int mi_ = 0; mi_ < 4; ++mi_) {                      \
      _Pragma("unroll") for (int ni_ = 0; ni_ < 4; ++ni_) {                    \
        acc[mi_][ni_] = mfma_bf16(af[mi_], BC[ni_], acc[mi_][ni_]);            \
      }                                                                        \
    }                                                                          \
    __builtin_amdgcn_s_setprio(0);                                             \
    asm volatile("s_waitcnt vmcnt(6)" ::: "memory");                           \
    asm volatile("" ::: "memory");                                             \
    __builtin_amdgcn_s_barrier();                                              \
    asm volatile("" ::: "memory");                                             \
  }

  // 6-phase groups: slot pattern (0,1,2)x2, B buffers alternate each phase
#pragma unroll 1
  for (int it = 0; it < 5; ++it) {
    const int p = it * 6;
    PH(0, 2, p + 0, bcur, bnxt)
    PH(1, 0, p + 1, bnxt, bcur)
    PH(2, 1, p + 2, bcur, bnxt)
    PH(0, 2, p + 3, bnxt, bcur)
    PH(1, 0, p + 4, bcur, bnxt)
    PH(2, 1, p + 5, bnxt, bcur)
  }
  PH(0, 2, 30, bcur, bnxt)
  PH(1, 0, 31, bnxt, bcur)
#undef PH
  asm volatile("s_waitcnt vmcnt(0)" ::: "memory");

  // epilogue: packed QK (Q pre-scaled) or V^T
  if (n0 < 2 * Cn) {
    const float sc = (n0 < Cn) ? SLOG2E : 1.f;
#pragma unroll
    for (int mi = 0; mi < 4; ++mi) {
#pragma unroll
      for (int ni = 0; ni < 4; ++ni) {
        const int col = n0 + wc * 64 + ni * 16 + l16;
        const int row = m0 + wr * 64 + mi * 16 + quad * 4;
#pragma unroll
        for (int i = 0; i < 4; ++i)
          qk[(size_t)(row + i) * QKS + col] = f2bf(acc[mi][ni][i] * sc);
      }
    }
  } else {
#pragma unroll
    for (int mi = 0; mi < 4; ++mi) {
#pragma unroll
      for (int ni = 0; ni < 4; ++ni) {
        const int colV = n0 - 2 * Cn + wc * 64 + ni * 16 + l16;  // 0..1023
        const int hh = colV >> 6, dd = colV & 63;
        const int row0 = m0 + wr * 64 + mi * 16 + quad * 4;
        const int bb = row0 >> 10, tt = row0 & 1023;
        unsigned int lo = (unsigned int)f2bf(acc[mi][ni][0]) |
                          ((unsigned int)f2bf(acc[mi][ni][1]) << 16);
        unsigned int hi = (unsigned int)f2bf(acc[mi][ni][2]) |
                          ((unsigned int)f2bf(acc[mi][ni][3]) << 16);
        uint2 pk = {lo, hi};
        *(uint2*)&vt[((size_t)(bb * Hn + hh) * Dn + dd) * Tn + tt] = pk;
      }
    }
  }
}

// ---------------- proj GEMM body (R5-best): BM=128, 4 waves, 3-slot rotation ------
template <int BM>
__device__ __forceinline__ void gemm_body4(
    const u16* __restrict__ A, const u16* __restrict__ Bw,
    float* __restrict__ Cout, const float* __restrict__ bias) {
  constexpr int ASLOT = BM * 32;
  constexpr int BSLOT = 128 * 32;
  constexpr int BBASE = 3 * ASLOT;
  constexpr int ASW = BM / 64;
  constexpr int BSW = 2;
  constexpr int LOADS = ASW + BSW;
  constexpr int MREP = BM / 32;
  constexpr int MT = Mn / BM;
  constexpr int MPX = MT / 8;

  __shared__ alignas(16) u16 lds[3 * (ASLOT + BSLOT)];

  const int tid = threadIdx.x;
  const int lane = tid & 63;
  const int wv = tid >> 6;
  const int quad = lane >> 4;
  const int l16 = lane & 15;
  const int wr = wv >> 1;
  const int wc = wv & 1;

  const int xcd = blockIdx.x & 7;
  const int loc = blockIdx.x >> 3;
  const int m0 = (xcd * MPX + (loc & (MPX - 1))) * BM;
  const int n0 = (loc / MPX) * 128;

  const u16* gA = A + (size_t)m0 * Cn;
  const u16* gB = Bw + (size_t)n0 * Cn;

  int soff[4];
#pragma unroll
  for (int s = 0; s < 4; ++s) {
    int c = s * 256 + tid;
    int row = c >> 2;
    int q = (c & 3) ^ ((row >> 1) & 3);
    soff[s] = row * Cn + q * 8;
  }

  auto stage = [&](int slot, int h) {
    const u16* sA = gA + (h >> 1) * 64 + (h & 1) * 32;
    u16* dA = lds + slot * ASLOT + tid * 8;
#pragma unroll
    for (int s = 0; s < ASW; ++s) async16(sA + soff[s], dA + s * 2048);
    const u16* sB = gB + (h >> 1) * 64 + (h & 1) * 32;
    u16* dB = lds + BBASE + slot * BSLOT + tid * 8;
#pragma unroll
    for (int s = 0; s < BSW; ++s) async16(sB + soff[s], dB + s * 2048);
  };

  const int sread = (quad ^ ((l16 >> 1) & 3)) * 8;
  const int aoff = (wr * (BM / 2) + l16) * 32 + sread;
  const int boff = BBASE + (wc * 64 + l16) * 32 + sread;

  f32x4 acc[MREP][4];
#pragma unroll
  for (int i = 0; i < MREP; ++i)
#pragma unroll
    for (int jj = 0; jj < 4; ++jj) acc[i][jj] = (f32x4){0.f, 0.f, 0.f, 0.f};
  ushx8 af[MREP], bfr[4];

  stage(0, 0);
  stage(1, 1);
  if constexpr (LOADS == 6) asm volatile("s_waitcnt vmcnt(6)" ::: "memory");
  else asm volatile("s_waitcnt vmcnt(4)" ::: "memory");
  __builtin_amdgcn_s_barrier();
  asm volatile("" ::: "memory");

#define PH(slot, sslot, hd)                                                    \
  {                                                                            \
    const u16* ab_ = lds + (slot) * ASLOT + aoff;                              \
    _Pragma("unroll") for (int mi_ = 0; mi_ < MREP; ++mi_)                     \
      af[mi_] = *(const ushx8*)(ab_ + mi_ * 512);                              \
    const u16* bb_ = lds + (slot) * BSLOT + boff;                              \
    _Pragma("unroll") for (int ni_ = 0; ni_ < 4; ++ni_)                        \
      bfr[ni_] = *(const ushx8*)(bb_ + ni_ * 512);                             \
    stage((sslot), (hd));                                                      \
    asm volatile("" ::: "memory");                                             \
    __builtin_amdgcn_s_barrier();                                              \
    asm volatile("s_waitcnt lgkmcnt(0)" ::: "memory");                         \
    __builtin_amdgcn_s_setprio(1);                                             \
    _Pragma("unroll") for (int mi_ = 0; mi_ < MREP; ++mi_) {                   \
      _Pragma("unroll") for (int ni_ = 0; ni_ < 4; ++ni_) {                    \
        acc[mi_][ni_] = mfma_bf16(af[mi_], bfr[ni_], acc[mi_][ni_]);           \
      }                                                                        \
    }                                                                          \
    __builtin_amdgcn_s_setprio(0);                                             \
    if constexpr (LOADS == 6)                                                  \
      asm volatile("s_waitcnt vmcnt(6)" ::: "memory");                         \
    else                                                                       \
      asm volatile("s_waitcnt vmcnt(4)" ::: "memory");                         \
    asm volatile("" ::: "memory");                                             \
    __builtin_amdgcn_s_barrier();                                              \
    asm volatile("" ::: "memory");                                             \
  }

#pragma unroll 1
  for (int it = 0; it < 5; ++it) {
    const int p = it * 6;
    PH(0, 2, p + 2)
    PH(1, 0, p + 3)
    PH(2, 1, p + 4)
    PH(0, 2, p + 5)
    PH(1, 0, p + 6)
    PH(2, 1, p + 7)
  }
  PH(0, 2, 31)
  PH(1, 0, 31)
#undef PH
  asm volatile("s_waitcnt vmcnt(0)" ::: "memory");

#pragma unroll
  for (int mi = 0; mi < MREP; ++mi) {
#pragma unroll
    for (int ni = 0; ni < 4; ++ni) {
      const int col = n0 + wc * 64 + ni * 16 + l16;
      const float bv = bias[col];
      const int row = m0 + wr * (BM / 2) + mi * 16 + quad * 4;
#pragma unroll
      for (int i = 0; i < 4; ++i)
        Cout[(size_t)(row + i) * Cn + col] = acc[mi][ni][i] + bv;
    }
  }
}

__global__ __launch_bounds__(256, 2) void gemm_proj_k(
    const u16* __restrict__ A, const u16* __restrict__ Bw,
    float* __restrict__ out, const float* __restrict__ bias) {
  gemm_body4<128>(A, Bw, out, bias);
}

// ---------------- flash attention v6: 3-slot K/V rotation + tile-pair pipeline ----
// 512 blocks (4,16,8) x 512 threads (8 waves). Block j does 128-row q-tiles
// j and 7-j. Wave wv owns q rows [wv*16, wv*16+16); one diagonal kv-tile each.
// K/V in 3 LDS slots (slot = tile % 3): at a pair (t,t+1)'s top barrier BOTH
// tiles are staged-and-drained, so QK^T(t+1) issues before softmax(t) —
// its MFMA overlaps softmax's VALU chain and P(t)'s LDS write->read latency.
__global__ __launch_bounds__(512, 4) void attn_kernel(
    const u16* __restrict__ qk, const u16* __restrict__ vt,
    u16* __restrict__ out) {
  const int j = blockIdx.x, h = blockIdx.y, b = blockIdx.z;
  const int tid = threadIdx.x;
  const int lane = tid & 63;
  const int wv = tid >> 6;           // 0..7
  const int quad = lane >> 4;
  const int l16 = lane & 15;

  __shared__ alignas(16) u16 Ks[3][64 * 64];   // [slot][kv][d] XOR-swizzled
  __shared__ alignas(16) u16 Vts[3][64 * 64];  // [slot][d][kv] XOR-swizzled
  __shared__ alignas(16) u16 Ps[8][16 * 72];   // per-wave P

  const u16* qb = qk + (size_t)b * Tn * QKS + h * Dn;
  const u16* kb = qk + (size_t)b * Tn * QKS + Cn + h * Dn;
  const u16* vtb = vt + (size_t)(b * Hn + h) * Dn * Tn;

  const int srow = tid >> 3;  // 0..63
  const int sgc = (tid & 7) ^ (srow & 7);
  u16* pswv = Ps[wv];

  auto stageKV = [&](int slot, int kt) {
    const int kv0s = kt * 64;
    async16(kb + (size_t)(kv0s + srow) * QKS + sgc * 8, Ks[slot] + tid * 8);
    async16(vtb + (size_t)srow * Tn + kv0s + sgc * 8, Vts[slot] + tid * 8);
  };

#pragma unroll 1
  for (int ph = 0; ph < 2; ++ph) {
    const int qt = ph ? (7 - j) : j;
    const int q0w = qt * 128 + wv * 16;   // this wave's first q row
    const int ntiles = 2 * qt + 2;        // even
    const int tdiag = q0w >> 6;           // wave's diagonal tile index

    // Q fragments (A-operand: m=l16, k=quad*8+jj); already scaled by SLOG2E
    ushx8 qf[2];
    {
      const u16* qp = qb + (size_t)(q0w + l16) * QKS + quad * 8;
      qf[0] = *(const ushx8*)qp;
      qf[1] = *(const ushx8*)(qp + 32);
    }

    f32x4 o[4];
#pragma unroll
    for (int nt = 0; nt < 4; ++nt) o[nt] = (f32x4){0.f, 0.f, 0.f, 0.f};
    float mrow[4], lrow[4];
#pragma unroll
    for (int i = 0; i < 4; ++i) { mrow[i] = -__builtin_inff(); lrow[i] = 0.f; }

    // S = Q K^T for one tile (8 MFMA), into s[4]
    auto qkt = [&](f32x4* s, const u16* ks) {
#pragma unroll
      for (int nt = 0; nt < 4; ++nt) s[nt] = (f32x4){0.f, 0.f, 0.f, 0.f};
#pragma unroll
      for (int nt = 0; nt < 4; ++nt) {
        const int rb = nt * 16 + l16;
        ushx8 b0 = *(const ushx8*)(ks + rb * 64 + (quad ^ (rb & 7)) * 8);
        ushx8 b1 = *(const ushx8*)(ks + rb * 64 + ((quad + 4) ^ (rb & 7)) * 8);
        s[nt] = mfma_bf16(qf[0], b0, s[nt]);
        s[nt] = mfma_bf16(qf[1], b1, s[nt]);
      }
    };

    // online softmax + P store/load + PV for one tile
    auto smpv = [&](f32x4* s, int tt, const u16* vs) {
      const int kv0 = tt * 64;
      if (tt == tdiag) {
#pragma unroll
        for (int i = 0; i < 4; ++i) {
          const int qr = q0w + quad * 4 + i;
          float vv[4];
          float rmax = -__builtin_inff();
#pragma unroll
          for (int nt = 0; nt < 4; ++nt) {
            float v = s[nt][i];
            if ((kv0 + nt * 16 + l16) > qr) v = -__builtin_inff();
            vv[nt] = v;
            rmax = fmaxf(rmax, v);
          }
          rmax = red16max(rmax);
          const float mnew = fmaxf(mrow[i], rmax);
          const float al = __builtin_amdgcn_exp2f(mrow[i] - mnew);
          mrow[i] = mnew;
          float rsum = 0.f;
#pragma unroll
          for (int nt = 0; nt < 4; ++nt) {
            float p = __builtin_amdgcn_exp2f(vv[nt] - mnew);
            rsum += p;
            pswv[(quad * 4 + i) * 72 + nt * 16 + l16] = f2bf_rna(p);
          }
          lrow[i] = lrow[i] * al + rsum;
#pragma unroll
          for (int nt = 0; nt < 4; ++nt) o[nt][i] *= al;
        }
      } else {
#pragma unroll
        for (int i = 0; i < 4; ++i) {
          float rmax = fmaxf(fmaxf(s[0][i], s[1][i]), fmaxf(s[2][i], s[3][i]));
          rmax = red16max(rmax);
          const float mnew = fmaxf(mrow[i], rmax);
          const float al = __builtin_amdgcn_exp2f(mrow[i] - mnew);
          mrow[i] = mnew;
          float rsum = 0.f;
#pragma unroll
          for (int nt = 0; nt < 4; ++nt) {
            float p = __builtin_amdgcn_exp2f(s[nt][i] - mnew);
            rsum += p;
            pswv[(quad * 4 + i) * 72 + nt * 16 + l16] = f2bf_rna(p);
          }
          lrow[i] = lrow[i] * al + rsum;
#pragma unroll
          for (int nt = 0; nt < 4; ++nt) o[nt][i] *= al;
        }
      }
      // P A-fragments from wave-local LDS (DS in-order per wave)
      ushx8 pf0, pf1;
      {
        const u16* pp = pswv + l16 * 72 + quad * 8;
        pf0 = *(const ushx8*)pp;
        pf1 = *(const ushx8*)(pp + 32);
      }
      // O += P V
#pragma unroll
      for (int nt = 0; nt < 4; ++nt) {
        const int rb = nt * 16 + l16;
        ushx8 v0 = *(const ushx8*)(vs + rb * 64 + (quad ^ (rb & 7)) * 8);
        ushx8 v1 = *(const ushx8*)(vs + rb * 64 + ((quad + 4) ^ (rb & 7)) * 8);
        o[nt] = mfma_bf16(pf0, v0, o[nt]);
        o[nt] = mfma_bf16(pf1, v1, o[nt]);
      }
    };

    __syncthreads();  // previous phase's readers done before restaging slots
    stageKV(0, 0);
    stageKV(1, 1);

#pragma unroll 1
    for (int t = 0; t < ntiles; t += 2) {
      const int s0 = t % 3;
      const int s1 = (t + 1) % 3;
      __syncthreads();  // drains DMA for tiles t, t+1; readers of slot (t+2)%3 done

      if (t + 2 < ntiles) stageKV((t + 2) % 3, t + 2);

      const bool a1 = (t <= tdiag);          // wave-uniform
      const bool a2 = (t + 1 <= tdiag);

      f32x4 sA[4], sB[4];
      if (a1) qkt(sA, Ks[s0]);
      if (a2) qkt(sB, Ks[s1]);               // hoisted: overlaps softmax(t) below
      if (a1) smpv(sA, t, Vts[s0]);

      __syncthreads();  // readers of slot t%3 (QK/PV of t) done
      if (t + 3 < ntiles) stageKV((t + 3) % 3, t + 3);

      if (a2) smpv(sB, t + 1, Vts[s1]);
    }

    // O/l (16-lane l reduction deferred to here), write y_attn bf16
#pragma unroll
    for (int i = 0; i < 4; ++i) {
      const float inv = 1.f / red16sum(lrow[i]);
      const int trow = q0w + quad * 4 + i;
      u16* op = out + ((size_t)(b * Tn + trow)) * Cn + h * Dn + l16;
#pragma unroll
      for (int nt = 0; nt < 4; ++nt) op[nt * 16] = f2bf(o[nt][i] * inv);
    }
  }
}

// ---------------- launch ----------------
extern "C" void kernel_launch(void* const* d_in, const int* in_sizes, int n_in,
                              void* d_out, int out_size, void* d_ws, size_t ws_size,
                              hipStream_t stream) {
  const float* x = (const float*)d_in[0];
  const float* w_qkv = (const float*)d_in[1];
  const float* w_proj = (const float*)d_in[2];
  const float* b_proj = (const float*)d_in[3];
  float* out = (float*)d_out;
  char* ws = (char*)d_ws;

  u16* xb     = (u16*)(ws);                 // 16 MiB @ 0
  u16* wqkvb  = (u16*)(ws + 16777216);      //  6 MiB @ 16  (B'[kb][n][32] layout)
  u16* wprojb = (u16*)(ws + 23068672);      //  2 MiB @ 22
  u16* qkb    = (u16*)(ws + 25165824);      // 32 MiB @ 24  (packed QK, stride 2048)
  u16* vtb    = (u16*)(ws + 58720256);      // 16 MiB @ 56
  u16* yb     = (u16*)(ws + 75497472);      // 16 MiB @ 72  (ends 88 MiB)

  cast3_kernel<<<12288, 256, 0, stream>>>(x, xb, 2097152,
                                          w_qkv, wqkvb, 786432,
                                          w_proj, wprojb, 262144);

  // QKV: 32 m-tiles x 24 n-tiles = 768 blocks (512 thr, 2 blocks/CU resident)
  gemm_qkv_k<<<768, 512, 0, stream>>>(xb, wqkvb, qkb, vtb);

  attn_kernel<<<dim3(4, Hn, Bn), 512, 0, stream>>>(qkb, vtb, yb);

  // proj: 64 m-tiles x 8 n-tiles = 512 blocks (256 thr, 2 blocks/CU)
  gemm_proj_k<<<512, 256, 0, stream>>>(yb, wprojb, out, b_proj);
}

// Round 8
// 214.644 us; speedup vs baseline: 1.1620x; 1.1620x over previous
//
#include <hip/hip_runtime.h>
#include <stdint.h>

// MHA forward, B=8 T=1024 C=1024 H=16 D=64.
// cast3 -> QKV GEMM (R4/R6-best: 256x128 tile, 8 waves/512thr, 3-slot rotation,
// counted vmcnt, 72 KiB -> 2 blocks/CU, 768 blocks)
// -> flash attention (3-slot K/V rotation + tile-pair pipelining + T13 defer-max
// + T5 setprio around MFMA clusters)
// -> proj GEMM (BM=128, 4 waves, 512 blocks = 2/CU, fp32 +bias). 4 launches.

#define Bn 8
#define Tn 1024
#define Cn 1024
#define Hn 16
#define Dn 64
#define Mn (Bn * Tn)      // 8192
#define NQKV (3 * Cn)     // 3072
#define QKS 2048          // packed QK row stride

typedef unsigned short u16;
typedef float f32x4 __attribute__((ext_vector_type(4)));
typedef __bf16 bf16x8 __attribute__((ext_vector_type(8)));
typedef unsigned short ushx8 __attribute__((ext_vector_type(8)));
typedef unsigned short ushx4 __attribute__((ext_vector_type(4)));

__device__ __forceinline__ u16 f2bf(float f) {
  unsigned int u = __float_as_uint(f);
  u += 0x7fffu + ((u >> 16) & 1u);   // RTN-even
  return (u16)(u >> 16);
}
__device__ __forceinline__ u16 f2bf_rna(float f) {
  return (u16)((__float_as_uint(f) + 0x8000u) >> 16);
}

__device__ __forceinline__ f32x4 mfma_bf16(ushx8 a, ushx8 b, f32x4 c) {
  return __builtin_amdgcn_mfma_f32_16x16x32_bf16(
      __builtin_bit_cast(bf16x8, a), __builtin_bit_cast(bf16x8, b), c, 0, 0, 0);
}

// async global->LDS, 16B per lane; LDS dest = wave-uniform base + lane*16 (m104)
__device__ __forceinline__ void async16(const u16* g, u16* l) {
  __builtin_amdgcn_global_load_lds(
      (__attribute__((address_space(1))) void*)(void*)g,
      (__attribute__((address_space(3))) void*)l, 16, 0, 0);
}

// ---- DPP 16-lane butterfly reductions (VALU-rate, no LDS pipe) ----
template <int CTRL>
__device__ __forceinline__ float dppmov(float v) {
  return __builtin_bit_cast(float, __builtin_amdgcn_update_dpp(
      0, __builtin_bit_cast(int, v), CTRL, 0xf, 0xf, true));
}
__device__ __forceinline__ float red16max(float v) {
  v = fmaxf(v, dppmov<0xB1>(v));
  v = fmaxf(v, dppmov<0x4E>(v));
  v = fmaxf(v, dppmov<0x141>(v));
  v = fmaxf(v, dppmov<0x140>(v));
  return v;
}
__device__ __forceinline__ float red16sum(float v) {
  v += dppmov<0xB1>(v);
  v += dppmov<0x4E>(v);
  v += dppmov<0x141>(v);
  v += dppmov<0x140>(v);
  return v;
}

// ---------------- fused cast fp32 -> bf16 (3 tensors, 1 launch) ----------------
__global__ void cast3_kernel(const float* __restrict__ a, u16* __restrict__ oa, int na4,
                             const float* __restrict__ b, u16* __restrict__ ob, int nb4,
                             const float* __restrict__ c, u16* __restrict__ oc, int nc4) {
  int i = blockIdx.x * blockDim.x + threadIdx.x;
  const float* in;
  u16* out;
  if (i < na4) { in = a; out = oa; }
  else if (i < na4 + nb4) { in = b; out = ob; i -= na4; }
  else if (i < na4 + nb4 + nc4) { in = c; out = oc; i -= na4 + nb4; }
  else return;
  float4 v = ((const float4*)in)[i];
  ushx4 o = { f2bf(v.x), f2bf(v.y), f2bf(v.z), f2bf(v.w) };
  ((ushx4*)out)[i] = o;
}

#define SLOG2E 0.18033688011112042f

// ---------------- QKV GEMM body (R4-best): 256x128, 8 waves, 3-slot rotation ----------
// 512 threads = 8 waves (4 M x 2 N); per-wave 64x64 output = acc[4][4].
// LDS 72 KiB: A = 3 slots x [256][32] u16 at 0; B = 3 slots x [128][32] at
// +24576 u16. Chunk swizzle p = q ^ ((row>>1)&3) (conflict-free, measured 0).
// 2 blocks/CU: partner block's MFMA covers this block's drain stalls.
// Phase p: read slot p%3 (h=p); stage h'=min(p+2,31) into slot (p+2)%3;
// barrier; lgkmcnt(0); 16 MFMA; vmcnt(3); barrier.
template <int MODE>
__device__ __forceinline__ void gemm_body(
    const u16* __restrict__ A, const u16* __restrict__ Bw,
    void* __restrict__ Cout, u16* __restrict__ vt,
    const float* __restrict__ bias) {
  __shared__ alignas(16) u16 lds[36864];  // 72 KiB

  const int tid = threadIdx.x;
  const int lane = tid & 63;
  const int wv = tid >> 6;       // 0..7
  const int quad = lane >> 4;
  const int l16 = lane & 15;
  const int wr = wv >> 1;        // 0..3 (M)
  const int wc = wv & 1;         // 0..1 (N)

  // XCD chunk map: xcd = bid&7 owns 4 consecutive 256-row m-tiles x all
  // n-tiles, m-fastest (A chunk 2 MiB fits XCD L2; B panel reused 4x).
  const int xcd = blockIdx.x & 7;
  const int loc = blockIdx.x >> 3;
  const int m0 = (xcd * 4 + (loc & 3)) * 256;
  const int n0 = (loc >> 2) * 128;

  const u16* gA = A + (size_t)m0 * Cn;
  const u16* gB = Bw + (size_t)n0 * Cn;

  const int r0s = tid >> 2;
  const int q0s = (tid & 3) ^ ((r0s >> 1) & 3);
  const int c1s = 512 + tid;
  const int r1s = c1s >> 2;
  const int q1s = (c1s & 3) ^ ((r1s >> 1) & 3);
  const int so0 = r0s * Cn + q0s * 8;
  const int so1 = r1s * Cn + q1s * 8;

  auto stageA = [&](int slot, int h) {
    u16* dst = lds + slot * 8192 + tid * 8;
    const u16* src = gA + (h >> 1) * 64 + (h & 1) * 32;
    async16(src + so0, dst);
    async16(src + so1, dst + 4096);
  };
  auto stageB = [&](int slot, int h) {
    u16* dst = lds + 24576 + slot * 4096 + tid * 8;
    const u16* src = gB + (h >> 1) * 64 + (h & 1) * 32;
    async16(src + so0, dst);
  };

  const int sread = (quad ^ ((l16 >> 1) & 3)) * 8;
  const int aoff = (wr * 64 + l16) * 32 + sread;
  const int boff = 24576 + (wc * 64 + l16) * 32 + sread;

  f32x4 acc[4][4];
#pragma unroll
  for (int i = 0; i < 4; ++i)
#pragma unroll
    for (int jj = 0; jj < 4; ++jj) acc[i][jj] = (f32x4){0.f, 0.f, 0.f, 0.f};
  ushx8 af[4], bfr[4];

  stageA(0, 0); stageB(0, 0);
  stageA(1, 1); stageB(1, 1);
  asm volatile("s_waitcnt vmcnt(3)" ::: "memory");
  __builtin_amdgcn_s_barrier();
  asm volatile("" ::: "memory");

#define PH(slot, sslot, hd)                                                    \
  {                                                                            \
    const u16* ab_ = lds + (slot) * 8192 + aoff;                               \
    af[0] = *(const ushx8*)(ab_);                                              \
    af[1] = *(const ushx8*)(ab_ + 512);                                        \
    af[2] = *(const ushx8*)(ab_ + 1024);                                       \
    af[3] = *(const ushx8*)(ab_ + 1536);                                       \
    const u16* bb_ = lds + (slot) * 4096 + boff;                               \
    bfr[0] = *(const ushx8*)(bb_);                                             \
    bfr[1] = *(const ushx8*)(bb_ + 512);                                       \
    bfr[2] = *(const ushx8*)(bb_ + 1024);                                      \
    bfr[3] = *(const ushx8*)(bb_ + 1536);                                      \
    stageA((sslot), (hd));                                                     \
    stageB((sslot), (hd));                                                     \
    asm volatile("" ::: "memory");                                             \
    __builtin_amdgcn_s_barrier();                                              \
    asm volatile("s_waitcnt lgkmcnt(0)" ::: "memory");                         \
    __builtin_amdgcn_s_setprio(1);                                             \
    _Pragma("unroll") for (int mi_ = 0; mi_ < 4; ++mi_) {                      \
      _Pragma("unroll") for (int ni_ = 0; ni_ < 4; ++ni_) {                    \
        acc[mi_][ni_] = mfma_bf16(af[mi_], bfr[ni_], acc[mi_][ni_]);           \
      }                                                                        \
    }                                                                          \
    __builtin_amdgcn_s_setprio(0);                                             \
    asm volatile("s_waitcnt vmcnt(3)" ::: "memory");                           \
    asm volatile("" ::: "memory");                                             \
    __builtin_amdgcn_s_barrier();                                              \
    asm volatile("" ::: "memory");                                             \
  }

#pragma unroll 1
  for (int it = 0; it < 5; ++it) {
    const int p = it * 6;
    PH(0, 2, p + 2)
    PH(1, 0, p + 3)
    PH(2, 1, p + 4)
    PH(0, 2, p + 5)
    PH(1, 0, p + 6)
    PH(2, 1, p + 7)
  }
  PH(0, 2, 31)
  PH(1, 0, 31)
#undef PH
  asm volatile("s_waitcnt vmcnt(0)" ::: "memory");

  if constexpr (MODE) {
    if (n0 < 2 * Cn) {
      const float sc = (n0 < Cn) ? SLOG2E : 1.f;
#pragma unroll
      for (int mi = 0; mi < 4; ++mi) {
#pragma unroll
        for (int ni = 0; ni < 4; ++ni) {
          const int col = n0 + wc * 64 + ni * 16 + l16;
          const int row = m0 + wr * 64 + mi * 16 + quad * 4;
#pragma unroll
          for (int i = 0; i < 4; ++i)
            ((u16*)Cout)[(size_t)(row + i) * QKS + col] = f2bf(acc[mi][ni][i] * sc);
        }
      }
    } else {
#pragma unroll
      for (int mi = 0; mi < 4; ++mi) {
#pragma unroll
        for (int ni = 0; ni < 4; ++ni) {
          const int colV = n0 - 2 * Cn + wc * 64 + ni * 16 + l16;  // 0..1023
          const int hh = colV >> 6, dd = colV & 63;
          const int row0 = m0 + wr * 64 + mi * 16 + quad * 4;
          const int bb = row0 >> 10, tt = row0 & 1023;
          unsigned int lo = (unsigned int)f2bf(acc[mi][ni][0]) |
                            ((unsigned int)f2bf(acc[mi][ni][1]) << 16);
          unsigned int hi = (unsigned int)f2bf(acc[mi][ni][2]) |
                            ((unsigned int)f2bf(acc[mi][ni][3]) << 16);
          uint2 pk = {lo, hi};
          *(uint2*)&vt[((size_t)(bb * Hn + hh) * Dn + dd) * Tn + tt] = pk;
        }
      }
    }
  } else {
#pragma unroll
    for (int mi = 0; mi < 4; ++mi) {
#pragma unroll
      for (int ni = 0; ni < 4; ++ni) {
        const int col = n0 + wc * 64 + ni * 16 + l16;
        const float bv = bias[col];
        const int row = m0 + wr * 64 + mi * 16 + quad * 4;
#pragma unroll
        for (int i = 0; i < 4; ++i)
          ((float*)Cout)[(size_t)(row + i) * Cn + col] = acc[mi][ni][i] + bv;
      }
    }
  }
}

// ---------------- proj GEMM body (R5-best): BM=128, 4 waves, 3-slot rotation ------
template <int BM>
__device__ __forceinline__ void gemm_body4(
    const u16* __restrict__ A, const u16* __restrict__ Bw,
    float* __restrict__ Cout, const float* __restrict__ bias) {
  constexpr int ASLOT = BM * 32;
  constexpr int BSLOT = 128 * 32;
  constexpr int BBASE = 3 * ASLOT;
  constexpr int ASW = BM / 64;
  constexpr int BSW = 2;
  constexpr int LOADS = ASW + BSW;
  constexpr int MREP = BM / 32;
  constexpr int MT = Mn / BM;
  constexpr int MPX = MT / 8;

  __shared__ alignas(16) u16 lds[3 * (ASLOT + BSLOT)];

  const int tid = threadIdx.x;
  const int lane = tid & 63;
  const int wv = tid >> 6;
  const int quad = lane >> 4;
  const int l16 = lane & 15;
  const int wr = wv >> 1;
  const int wc = wv & 1;

  const int xcd = blockIdx.x & 7;
  const int loc = blockIdx.x >> 3;
  const int m0 = (xcd * MPX + (loc & (MPX - 1))) * BM;
  const int n0 = (loc / MPX) * 128;

  const u16* gA = A + (size_t)m0 * Cn;
  const u16* gB = Bw + (size_t)n0 * Cn;

  int soff[4];
#pragma unroll
  for (int s = 0; s < 4; ++s) {
    int c = s * 256 + tid;
    int row = c >> 2;
    int q = (c & 3) ^ ((row >> 1) & 3);
    soff[s] = row * Cn + q * 8;
  }

  auto stage = [&](int slot, int h) {
    const u16* sA = gA + (h >> 1) * 64 + (h & 1) * 32;
    u16* dA = lds + slot * ASLOT + tid * 8;
#pragma unroll
    for (int s = 0; s < ASW; ++s) async16(sA + soff[s], dA + s * 2048);
    const u16* sB = gB + (h >> 1) * 64 + (h & 1) * 32;
    u16* dB = lds + BBASE + slot * BSLOT + tid * 8;
#pragma unroll
    for (int s = 0; s < BSW; ++s) async16(sB + soff[s], dB + s * 2048);
  };

  const int sread = (quad ^ ((l16 >> 1) & 3)) * 8;
  const int aoff = (wr * (BM / 2) + l16) * 32 + sread;
  const int boff = BBASE + (wc * 64 + l16) * 32 + sread;

  f32x4 acc[MREP][4];
#pragma unroll
  for (int i = 0; i < MREP; ++i)
#pragma unroll
    for (int jj = 0; jj < 4; ++jj) acc[i][jj] = (f32x4){0.f, 0.f, 0.f, 0.f};
  ushx8 af[MREP], bfr[4];

  stage(0, 0);
  stage(1, 1);
  if constexpr (LOADS == 6) asm volatile("s_waitcnt vmcnt(6)" ::: "memory");
  else asm volatile("s_waitcnt vmcnt(4)" ::: "memory");
  __builtin_amdgcn_s_barrier();
  asm volatile("" ::: "memory");

#define PH(slot, sslot, hd)                                                    \
  {                                                                            \
    const u16* ab_ = lds + (slot) * ASLOT + aoff;                              \
    _Pragma("unroll") for (int mi_ = 0; mi_ < MREP; ++mi_)                     \
      af[mi_] = *(const ushx8*)(ab_ + mi_ * 512);                              \
    const u16* bb_ = lds + (slot) * BSLOT + boff;                              \
    _Pragma("unroll") for (int ni_ = 0; ni_ < 4; ++ni_)                        \
      bfr[ni_] = *(const ushx8*)(bb_ + ni_ * 512);                             \
    stage((sslot), (hd));                                                      \
    asm volatile("" ::: "memory");                                             \
    __builtin_amdgcn_s_barrier();                                              \
    asm volatile("s_waitcnt lgkmcnt(0)" ::: "memory");                         \
    __builtin_amdgcn_s_setprio(1);                                             \
    _Pragma("unroll") for (int mi_ = 0; mi_ < MREP; ++mi_) {                   \
      _Pragma("unroll") for (int ni_ = 0; ni_ < 4; ++ni_) {                    \
        acc[mi_][ni_] = mfma_bf16(af[mi_], bfr[ni_], acc[mi_][ni_]);           \
      }                                                                        \
    }                                                                          \
    __builtin_amdgcn_s_setprio(0);                                             \
    if constexpr (LOADS == 6)                                                  \
      asm volatile("s_waitcnt vmcnt(6)" ::: "memory");                         \
    else                                                                       \
      asm volatile("s_waitcnt vmcnt(4)" ::: "memory");                         \
    asm volatile("" ::: "memory");                                             \
    __builtin_amdgcn_s_barrier();                                              \
    asm volatile("" ::: "memory");                                             \
  }

#pragma unroll 1
  for (int it = 0; it < 5; ++it) {
    const int p = it * 6;
    PH(0, 2, p + 2)
    PH(1, 0, p + 3)
    PH(2, 1, p + 4)
    PH(0, 2, p + 5)
    PH(1, 0, p + 6)
    PH(2, 1, p + 7)
  }
  PH(0, 2, 31)
  PH(1, 0, 31)
#undef PH
  asm volatile("s_waitcnt vmcnt(0)" ::: "memory");

#pragma unroll
  for (int mi = 0; mi < MREP; ++mi) {
#pragma unroll
    for (int ni = 0; ni < 4; ++ni) {
      const int col = n0 + wc * 64 + ni * 16 + l16;
      const float bv = bias[col];
      const int row = m0 + wr * (BM / 2) + mi * 16 + quad * 4;
#pragma unroll
      for (int i = 0; i < 4; ++i)
        Cout[(size_t)(row + i) * Cn + col] = acc[mi][ni][i] + bv;
    }
  }
}

__global__ __launch_bounds__(512, 4) void gemm_qkv_k(
    const u16* __restrict__ A, const u16* __restrict__ Bw,
    u16* __restrict__ qk, u16* __restrict__ vt) {
  gemm_body<1>(A, Bw, (void*)qk, vt, nullptr);
}
__global__ __launch_bounds__(256, 2) void gemm_proj_k(
    const u16* __restrict__ A, const u16* __restrict__ Bw,
    float* __restrict__ out, const float* __restrict__ bias) {
  gemm_body4<128>(A, Bw, out, bias);
}

// ---------------- flash attention v7: v6 + T13 defer-max + T5 setprio ----
// 512 blocks (4,16,8) x 512 threads (8 waves). Block j does 128-row q-tiles
// j and 7-j. K/V in 3 LDS slots; QK^T(t+1) hoisted over softmax(t).
// T13: keep running max unless new tile max exceeds it by >8 (P bounded by
// 2^8, bf16-safe; math identical when m unchanged) -> skips the O-wide
// rescale on most tiles. T5: setprio(1) around MFMA clusters.
__global__ __launch_bounds__(512, 4) void attn_kernel(
    const u16* __restrict__ qk, const u16* __restrict__ vt,
    u16* __restrict__ out) {
  const int j = blockIdx.x, h = blockIdx.y, b = blockIdx.z;
  const int tid = threadIdx.x;
  const int lane = tid & 63;
  const int wv = tid >> 6;           // 0..7
  const int quad = lane >> 4;
  const int l16 = lane & 15;

  __shared__ alignas(16) u16 Ks[3][64 * 64];   // [slot][kv][d] XOR-swizzled
  __shared__ alignas(16) u16 Vts[3][64 * 64];  // [slot][d][kv] XOR-swizzled
  __shared__ alignas(16) u16 Ps[8][16 * 72];   // per-wave P

  const u16* qb = qk + (size_t)b * Tn * QKS + h * Dn;
  const u16* kb = qk + (size_t)b * Tn * QKS + Cn + h * Dn;
  const u16* vtb = vt + (size_t)(b * Hn + h) * Dn * Tn;

  const int srow = tid >> 3;  // 0..63
  const int sgc = (tid & 7) ^ (srow & 7);
  u16* pswv = Ps[wv];

  auto stageKV = [&](int slot, int kt) {
    const int kv0s = kt * 64;
    async16(kb + (size_t)(kv0s + srow) * QKS + sgc * 8, Ks[slot] + tid * 8);
    async16(vtb + (size_t)srow * Tn + kv0s + sgc * 8, Vts[slot] + tid * 8);
  };

#pragma unroll 1
  for (int ph = 0; ph < 2; ++ph) {
    const int qt = ph ? (7 - j) : j;
    const int q0w = qt * 128 + wv * 16;   // this wave's first q row
    const int ntiles = 2 * qt + 2;        // even
    const int tdiag = q0w >> 6;           // wave's diagonal tile index

    // Q fragments (A-operand: m=l16, k=quad*8+jj); already scaled by SLOG2E
    ushx8 qf[2];
    {
      const u16* qp = qb + (size_t)(q0w + l16) * QKS + quad * 8;
      qf[0] = *(const ushx8*)qp;
      qf[1] = *(const ushx8*)(qp + 32);
    }

    f32x4 o[4];
#pragma unroll
    for (int nt = 0; nt < 4; ++nt) o[nt] = (f32x4){0.f, 0.f, 0.f, 0.f};
    float mrow[4], lrow[4];
#pragma unroll
    for (int i = 0; i < 4; ++i) { mrow[i] = -__builtin_inff(); lrow[i] = 0.f; }

    // S = Q K^T for one tile (8 MFMA), into s[4]
    auto qkt = [&](f32x4* s, const u16* ks) {
#pragma unroll
      for (int nt = 0; nt < 4; ++nt) s[nt] = (f32x4){0.f, 0.f, 0.f, 0.f};
      __builtin_amdgcn_s_setprio(1);
#pragma unroll
      for (int nt = 0; nt < 4; ++nt) {
        const int rb = nt * 16 + l16;
        ushx8 b0 = *(const ushx8*)(ks + rb * 64 + (quad ^ (rb & 7)) * 8);
        ushx8 b1 = *(const ushx8*)(ks + rb * 64 + ((quad + 4) ^ (rb & 7)) * 8);
        s[nt] = mfma_bf16(qf[0], b0, s[nt]);
        s[nt] = mfma_bf16(qf[1], b1, s[nt]);
      }
      __builtin_amdgcn_s_setprio(0);
    };

    // online softmax (T13 defer-max) + P store/load + PV for one tile
    auto smpv = [&](f32x4* s, int tt, const u16* vs) {
      const int kv0 = tt * 64;
      if (tt == tdiag) {
#pragma unroll
        for (int i = 0; i < 4; ++i) {
          const int qr = q0w + quad * 4 + i;
          float vv[4];
          float rmax = -__builtin_inff();
#pragma unroll
          for (int nt = 0; nt < 4; ++nt) {
            float v = s[nt][i];
            if ((kv0 + nt * 16 + l16) > qr) v = -__builtin_inff();
            vv[nt] = v;
            rmax = fmaxf(rmax, v);
          }
          rmax = red16max(rmax);
          if (rmax - mrow[i] > 8.f) {      // uniform within 16-lane group
            const float al = __builtin_amdgcn_exp2f(mrow[i] - rmax);
            mrow[i] = rmax;
            lrow[i] *= al;
#pragma unroll
            for (int nt = 0; nt < 4; ++nt) o[nt][i] *= al;
          }
          float rsum = 0.f;
#pragma unroll
          for (int nt = 0; nt < 4; ++nt) {
            float p = __builtin_amdgcn_exp2f(vv[nt] - mrow[i]);
            rsum += p;
            pswv[(quad * 4 + i) * 72 + nt * 16 + l16] = f2bf_rna(p);
          }
          lrow[i] += rsum;
        }
      } else {
#pragma unroll
        for (int i = 0; i < 4; ++i) {
          float rmax = fmaxf(fmaxf(s[0][i], s[1][i]), fmaxf(s[2][i], s[3][i]));
          rmax = red16max(rmax);
          if (rmax - mrow[i] > 8.f) {
            const float al = __builtin_amdgcn_exp2f(mrow[i] - rmax);
            mrow[i] = rmax;
            lrow[i] *= al;
#pragma unroll
            for (int nt = 0; nt < 4; ++nt) o[nt][i] *= al;
          }
          float rsum = 0.f;
#pragma unroll
          for (int nt = 0; nt < 4; ++nt) {
            float p = __builtin_amdgcn_exp2f(s[nt][i] - mrow[i]);
            rsum += p;
            pswv[(quad * 4 + i) * 72 + nt * 16 + l16] = f2bf_rna(p);
          }
          lrow[i] += rsum;
        }
      }
      // P A-fragments from wave-local LDS (DS in-order per wave)
      ushx8 pf0, pf1;
      {
        const u16* pp = pswv + l16 * 72 + quad * 8;
        pf0 = *(const ushx8*)pp;
        pf1 = *(const ushx8*)(pp + 32);
      }
      // O += P V
      __builtin_amdgcn_s_setprio(1);
#pragma unroll
      for (int nt = 0; nt < 4; ++nt) {
        const int rb = nt * 16 + l16;
        ushx8 v0 = *(const ushx8*)(vs + rb * 64 + (quad ^ (rb & 7)) * 8);
        ushx8 v1 = *(const ushx8*)(vs + rb * 64 + ((quad + 4) ^ (rb & 7)) * 8);
        o[nt] = mfma_bf16(pf0, v0, o[nt]);
        o[nt] = mfma_bf16(pf1, v1, o[nt]);
      }
      __builtin_amdgcn_s_setprio(0);
    };

    __syncthreads();  // previous phase's readers done before restaging slots
    stageKV(0, 0);
    stageKV(1, 1);

#pragma unroll 1
    for (int t = 0; t < ntiles; t += 2) {
      const int s0 = t % 3;
      const int s1 = (t + 1) % 3;
      __syncthreads();  // drains DMA for tiles t, t+1; readers of slot (t+2)%3 done

      if (t + 2 < ntiles) stageKV((t + 2) % 3, t + 2);

      const bool a1 = (t <= tdiag);          // wave-uniform
      const bool a2 = (t + 1 <= tdiag);

      f32x4 sA[4], sB[4];
      if (a1) qkt(sA, Ks[s0]);
      if (a2) qkt(sB, Ks[s1]);               // hoisted: overlaps softmax(t) below
      if (a1) smpv(sA, t, Vts[s0]);

      __syncthreads();  // readers of slot t%3 (QK/PV of t) done
      if (t + 3 < ntiles) stageKV((t + 3) % 3, t + 3);

      if (a2) smpv(sB, t + 1, Vts[s1]);
    }

    // O/l (16-lane l reduction deferred to here), write y_attn bf16
#pragma unroll
    for (int i = 0; i < 4; ++i) {
      const float inv = 1.f / red16sum(lrow[i]);
      const int trow = q0w + quad * 4 + i;
      u16* op = out + ((size_t)(b * Tn + trow)) * Cn + h * Dn + l16;
#pragma unroll
      for (int nt = 0; nt < 4; ++nt) op[nt * 16] = f2bf(o[nt][i] * inv);
    }
  }
}

// ---------------- launch ----------------
extern "C" void kernel_launch(void* const* d_in, const int* in_sizes, int n_in,
                              void* d_out, int out_size, void* d_ws, size_t ws_size,
                              hipStream_t stream) {
  const float* x = (const float*)d_in[0];
  const float* w_qkv = (const float*)d_in[1];
  const float* w_proj = (const float*)d_in[2];
  const float* b_proj = (const float*)d_in[3];
  float* out = (float*)d_out;
  char* ws = (char*)d_ws;

  u16* xb     = (u16*)(ws);                 // 16 MiB @ 0
  u16* wqkvb  = (u16*)(ws + 16777216);      //  6 MiB @ 16
  u16* wprojb = (u16*)(ws + 23068672);      //  2 MiB @ 22
  u16* qkb    = (u16*)(ws + 25165824);      // 32 MiB @ 24  (packed QK, stride 2048)
  u16* vtb    = (u16*)(ws + 58720256);      // 16 MiB @ 56
  u16* yb     = (u16*)(ws + 75497472);      // 16 MiB @ 72  (ends 88 MiB)

  cast3_kernel<<<12288, 256, 0, stream>>>(x, xb, 2097152,
                                          w_qkv, wqkvb, 786432,
                                          w_proj, wprojb, 262144);

  // QKV: 32 m-tiles x 24 n-tiles = 768 blocks (512 thr, 2 blocks/CU)
  gemm_qkv_k<<<768, 512, 0, stream>>>(xb, wqkvb, qkb, vtb);

  attn_kernel<<<dim3(4, Hn, Bn), 512, 0, stream>>>(qkb, vtb, yb);

  // proj: 64 m-tiles x 8 n-tiles = 512 blocks (256 thr, 2 blocks/CU)
  gemm_proj_k<<<512, 256, 0, stream>>>(yb, wprojb, out, b_proj);
}